// Round 4
// baseline (1408.515 us; speedup 1.0000x reference)
//
#include <hip/hip_runtime.h>

#define VOCAB_ROWS 50001
#define EMB 32
#define UNITS 16
#define GATES 48
#define BATCH 256
#define SEQ 4096
#define LOG2E 1.4426950408889634f

// ---------------- Phase 1: per-vocab projection table ----------------
// proj[v][j] = (bias[0][j] + sum_e emb[v][e]*kernel[e][j]) * log2(e)
// log2(e) pre-scale lets the scan use exp2 directly (sigmoid = rcp(1+2^-y)).
__global__ __launch_bounds__(256) void proj_kernel(const float* __restrict__ emb,
                                                   const float* __restrict__ kern,
                                                   const float* __restrict__ bias,
                                                   float* __restrict__ proj) {
    int gid = blockIdx.x * 256 + threadIdx.x;
    if (gid >= VOCAB_ROWS * GATES) return;
    int v = gid / GATES;
    int j = gid - v * GATES;
    const float* erow = emb + v * EMB;
    float acc = bias[j];
#pragma unroll
    for (int e = 0; e < EMB; ++e)
        acc = fmaf(erow[e], kern[e * GATES + j], acc);
    proj[gid] = acc * LOG2E;
}

// ---------------- Phase 2: sequential GRU scan ----------------
// sigmoid on pre-scaled argument (inputs already multiplied by log2(e)):
// sig(x) = rcp(1 + 2^(-y)) ; v_exp_f32 computes 2^x, -y is a free input mod.
__device__ __forceinline__ float sig2(float y) {
    return __builtin_amdgcn_rcpf(1.0f + __builtin_amdgcn_exp2f(-y));
}

__device__ __forceinline__ float rdlane(float v, int l) {
    return __int_as_float(__builtin_amdgcn_readlane(__float_as_int(v), l));
}

// TWO batch rows per wave, temporally interleaved: row B's independent
// instruction stream fills row A's dependency-stall cycles (in-order wave).
// h broadcast via v_readlane -> SGPR (VALU pipe, no DS latency).
__global__ __launch_bounds__(64) void gru_scan(const int* __restrict__ ids,
                                               const float* __restrict__ reck,
                                               const float* __restrict__ bias,
                                               const float* __restrict__ proj,
                                               float* __restrict__ out) {
    const int lane = threadIdx.x & 63;
    const int u    = lane & 15;            // unit; lanes 16..63 mirror 0..15
    const int b0   = blockIdx.x * 2;
    const int b1   = b0 + 1;
    const int* __restrict__ idrow0 = ids + (size_t)b0 * SEQ;
    const int* __restrict__ idrow1 = ids + (size_t)b1 * SEQ;

    // recurrent weight columns for this unit (shared by both rows), pre-scaled
    float Rz[UNITS], Rr[UNITS], Rh[UNITS];
#pragma unroll
    for (int k = 0; k < UNITS; ++k) {
        Rz[k] = reck[k * GATES + u]      * LOG2E;
        Rr[k] = reck[k * GATES + 16 + u] * LOG2E;
        Rh[k] = reck[k * GATES + 32 + u] * LOG2E;
    }
    const float bz = bias[GATES + u]      * LOG2E;
    const float br = bias[GATES + 16 + u] * LOG2E;
    const float bh = bias[GATES + 32 + u] * LOG2E;

    // software-pipeline rings per row: x rows 8 ahead, ids 16 ahead
    float xa0[8], xa1[8], xa2[8], xb0[8], xb1[8], xb2[8];
    int   ida[8], idb[8];
#pragma unroll
    for (int s = 0; s < 8; ++s) {
        const float* pa = proj + (size_t)idrow0[s] * GATES;
        const float* pb = proj + (size_t)idrow1[s] * GATES;
        xa0[s] = pa[u]; xa1[s] = pa[16 + u]; xa2[s] = pa[32 + u];
        xb0[s] = pb[u]; xb1[s] = pb[16 + u]; xb2[s] = pb[32 + u];
        ida[s] = idrow0[8 + s];
        idb[s] = idrow1[8 + s];
    }

    float ha = 0.0f, hb = 0.0f;
    for (int t0 = 0; t0 < SEQ; t0 += 8) {
#pragma unroll
        for (int uu = 0; uu < 8; ++uu) {
            const int t = t0 + uu;
            int tf = t + 16;
            tf = tf < SEQ ? tf : SEQ - 1;

            // ---- prefetch both rows first (loads in flight over the math) ----
            const float* pa = proj + (size_t)ida[uu] * GATES;
            const float* pb = proj + (size_t)idb[uu] * GATES;
            const float paz = pa[u], par = pa[16 + u], pah = pa[32 + u];
            const float pbz = pb[u], pbr = pb[16 + u], pbh = pb[32 + u];
            ida[uu] = idrow0[tf];
            idb[uu] = idrow1[tf];

            // ---- row A step t ----
            {
                const float xz = xa0[uu], xr = xa1[uu], xh = xa2[uu];
                xa0[uu] = paz; xa1[uu] = par; xa2[uu] = pah;
                float az0 = bz, az1 = 0.f, ar0 = br, ar1 = 0.f, ah0 = bh, ah1 = 0.f;
#pragma unroll
                for (int k = 0; k < 8; ++k) {
                    const float h0 = rdlane(ha, k);
                    const float h1 = rdlane(ha, k + 8);
                    az0 = fmaf(Rz[k], h0, az0);  az1 = fmaf(Rz[k + 8], h1, az1);
                    ar0 = fmaf(Rr[k], h0, ar0);  ar1 = fmaf(Rr[k + 8], h1, ar1);
                    ah0 = fmaf(Rh[k], h0, ah0);  ah1 = fmaf(Rh[k + 8], h1, ah1);
                }
                const float z  = sig2(xz + az0 + az1);
                const float r  = sig2(xr + ar0 + ar1);
                const float hh = sig2(fmaf(r, ah0 + ah1, xh));
                ha = fmaf(z, ha - hh, hh);
            }

            // ---- row B step t (independent dataflow fills A's stalls) ----
            {
                const float xz = xb0[uu], xr = xb1[uu], xh = xb2[uu];
                xb0[uu] = pbz; xb1[uu] = pbr; xb2[uu] = pbh;
                float az0 = bz, az1 = 0.f, ar0 = br, ar1 = 0.f, ah0 = bh, ah1 = 0.f;
#pragma unroll
                for (int k = 0; k < 8; ++k) {
                    const float h0 = rdlane(hb, k);
                    const float h1 = rdlane(hb, k + 8);
                    az0 = fmaf(Rz[k], h0, az0);  az1 = fmaf(Rz[k + 8], h1, az1);
                    ar0 = fmaf(Rr[k], h0, ar0);  ar1 = fmaf(Rr[k + 8], h1, ar1);
                    ah0 = fmaf(Rh[k], h0, ah0);  ah1 = fmaf(Rh[k + 8], h1, ah1);
                }
                const float z  = sig2(xz + az0 + az1);
                const float r  = sig2(xr + ar0 + ar1);
                const float hh = sig2(fmaf(r, ah0 + ah1, xh));
                hb = fmaf(z, hb - hh, hh);
            }
        }
    }

    if (lane < UNITS) {
        out[b0 * UNITS + u] = ha;
        out[b1 * UNITS + u] = hb;
    }
}

extern "C" void kernel_launch(void* const* d_in, const int* in_sizes, int n_in,
                              void* d_out, int out_size, void* d_ws, size_t ws_size,
                              hipStream_t stream) {
    const int*   ids  = (const int*)d_in[0];
    const float* emb  = (const float*)d_in[1];
    const float* kern = (const float*)d_in[2];
    const float* reck = (const float*)d_in[3];
    const float* bias = (const float*)d_in[4];
    float* out  = (float*)d_out;
    float* proj = (float*)d_ws;   // 50001*48 floats = 9.6 MB scratch

    const int total = VOCAB_ROWS * GATES;
    proj_kernel<<<(total + 255) / 256, 256, 0, stream>>>(emb, kern, bias, proj);
    gru_scan<<<BATCH / 2, 64, 0, stream>>>(ids, reck, bias, proj, out);
}

// Round 5
// 1165.948 us; speedup vs baseline: 1.2080x; 1.2080x over previous
//
#include <hip/hip_runtime.h>

#define VOCAB_ROWS 50001
#define EMB 32
#define UNITS 16
#define GATES 48
#define BATCH 256
#define SEQ 4096
#define LOG2E 1.4426950408889634f

// ---------------- Phase 1: per-vocab projection table ----------------
// proj[v][j] = (bias[0][j] + sum_e emb[v][e]*kernel[e][j]) * log2(e)
// log2(e) pre-scale lets the scan use exp2 directly (sigmoid = rcp(1+2^-y)).
__global__ __launch_bounds__(256) void proj_kernel(const float* __restrict__ emb,
                                                   const float* __restrict__ kern,
                                                   const float* __restrict__ bias,
                                                   float* __restrict__ proj) {
    int gid = blockIdx.x * 256 + threadIdx.x;
    if (gid >= VOCAB_ROWS * GATES) return;
    int v = gid / GATES;
    int j = gid - v * GATES;
    const float* erow = emb + v * EMB;
    float acc = bias[j];
#pragma unroll
    for (int e = 0; e < EMB; ++e)
        acc = fmaf(erow[e], kern[e * GATES + j], acc);
    proj[gid] = acc * LOG2E;
}

// ---------------- Phase 2: sequential GRU scan ----------------
// sigmoid on pre-scaled argument: sig(x) = rcp(1 + 2^(-y)); v_exp_f32 = 2^x,
// the -y negate folds into a free VOP3 input modifier.
__device__ __forceinline__ float sig2(float y) {
    return __builtin_amdgcn_rcpf(1.0f + __builtin_amdgcn_exp2f(-y));
}

// Broadcast lane l -> SGPR (VALU pipe, ~5 cyc; no DS latency).
__device__ __forceinline__ float rdlane(float v, int l) {
    return __int_as_float(__builtin_amdgcn_readlane(__float_as_int(v), l));
}

// ONE batch row per wave, 256 waves = 1 wave/CU across the whole chip.
// __launch_bounds__(64, 1): we need exactly 1 wave/SIMD, so give the register
// allocator the full VGPR file -- R2/R4 showed VGPR_Count=48/68, i.e. the
// 48 recurrent weights were NOT register-resident (reloaded every step,
// ~150 extra issue-cycles/step). Keeping them resident is the whole round.
__global__ __launch_bounds__(64, 1) void gru_scan(const int* __restrict__ ids,
                                                  const float* __restrict__ reck,
                                                  const float* __restrict__ bias,
                                                  const float* __restrict__ proj,
                                                  float* __restrict__ out) {
    const int lane = threadIdx.x & 63;
    const int u    = lane & 15;          // unit; lanes 16..63 mirror lanes 0..15
    const int b    = blockIdx.x;
    const int* __restrict__ idrow = ids + (size_t)b * SEQ;

    // recurrent weight columns for this unit, pre-scaled by log2(e)
    float Rz[UNITS], Rr[UNITS], Rh[UNITS];
#pragma unroll
    for (int k = 0; k < UNITS; ++k) {
        Rz[k] = reck[k * GATES + u]      * LOG2E;
        Rr[k] = reck[k * GATES + 16 + u] * LOG2E;
        Rh[k] = reck[k * GATES + 32 + u] * LOG2E;
    }
    const float bz = bias[GATES + u]      * LOG2E;
    const float br = bias[GATES + 16 + u] * LOG2E;
    const float bh = bias[GATES + 32 + u] * LOG2E;

    // software-pipeline rings: x rows 8 ahead, ids 16 ahead
    float xq0[8], xq1[8], xq2[8];
    int   idq[8];
#pragma unroll
    for (int s = 0; s < 8; ++s) {
        const float* p = proj + (size_t)idrow[s] * GATES;
        xq0[s] = p[u]; xq1[s] = p[16 + u]; xq2[s] = p[32 + u];
        idq[s] = idrow[8 + s];
    }

    float h = 0.0f;
    for (int t0 = 0; t0 < SEQ; t0 += 8) {
#pragma unroll
        for (int uu = 0; uu < 8; ++uu) {
            const int t = t0 + uu;
            // consume step-t row (loaded 8 steps ago, already in registers)
            const float xz = xq0[uu], xr = xq1[uu], xh = xq2[uu];
            // prefetch: gather row t+8 (one base addr + 3 imm-offset loads),
            // scalar id for t+16
            const float* p = proj + (size_t)idq[uu] * GATES;
            xq0[uu] = p[u]; xq1[uu] = p[16 + u]; xq2[uu] = p[32 + u];
            int tf = t + 16;
            tf = tf < SEQ ? tf : SEQ - 1;
            idq[uu] = idrow[tf];

            // 16x48 matvec: 3 chains, 16 deep, round-robin issue (gap 6 cyc
            // > 4 cyc fma dep latency -> no intra-chain stall). Biases folded:
            // az/ar start at x-term, ah starts at bh (first-fma addend).
            float az = xz, ar = xr, ah = bh;
#pragma unroll
            for (int k = 0; k < UNITS; ++k) {
                const float hk = rdlane(h, k);
                az = fmaf(Rz[k], hk, az);
                ar = fmaf(Rr[k], hk, ar);
                ah = fmaf(Rh[k], hk, ah);
            }
            const float z  = sig2(az + bz);
            const float r  = sig2(ar + br);
            const float hh = sig2(fmaf(r, ah, xh));
            h = fmaf(z, h - hh, hh);     // z*h + (1-z)*hh
        }
    }

    if (lane < UNITS) out[b * UNITS + u] = h;
}

extern "C" void kernel_launch(void* const* d_in, const int* in_sizes, int n_in,
                              void* d_out, int out_size, void* d_ws, size_t ws_size,
                              hipStream_t stream) {
    const int*   ids  = (const int*)d_in[0];
    const float* emb  = (const float*)d_in[1];
    const float* kern = (const float*)d_in[2];
    const float* reck = (const float*)d_in[3];
    const float* bias = (const float*)d_in[4];
    float* out  = (float*)d_out;
    float* proj = (float*)d_ws;   // 50001*48 floats = 9.6 MB scratch

    const int total = VOCAB_ROWS * GATES;
    proj_kernel<<<(total + 255) / 256, 256, 0, stream>>>(emb, kern, bias, proj);
    gru_scan<<<BATCH, 64, 0, stream>>>(ids, reck, bias, proj, out);
}

// Round 7
// 1125.698 us; speedup vs baseline: 1.2512x; 1.0358x over previous
//
#include <hip/hip_runtime.h>

#define VOCAB_ROWS 50001
#define EMB 32
#define UNITS 16
#define GATES 48
#define BATCH 256
#define SEQ 4096
#define LOG2E 1.4426950408889634f

typedef float v2f __attribute__((ext_vector_type(2)));

__device__ __forceinline__ v2f mk2(float x, float y) { v2f r; r.x = x; r.y = y; return r; }
__device__ __forceinline__ v2f fma2(v2f a, float b, v2f c) {
    v2f bb; bb.x = b; bb.y = b;
    return __builtin_elementwise_fma(a, bb, c);
}

// ---------------- Phase 1: per-vocab projection table ----------------
// proj[v][j] = (bias0[j] + [j<32: rec_bias[j]] + sum_e emb[v][e]*kernel[e][j]) * log2(e)
// - log2(e) pre-scale: scan sigmoids become rcp(1 + 2^-y) (v_exp_f32 native).
// - recurrent z/r biases folded here (constant per j, OUTSIDE the reset gate);
//   h-gate recurrent bias must stay in the scan (inside r*(...), reset_after).
__global__ __launch_bounds__(256) void proj_kernel(const float* __restrict__ emb,
                                                   const float* __restrict__ kern,
                                                   const float* __restrict__ bias,
                                                   float* __restrict__ proj) {
    int gid = blockIdx.x * 256 + threadIdx.x;
    if (gid >= VOCAB_ROWS * GATES) return;
    int v = gid / GATES;
    int j = gid - v * GATES;
    const float* erow = emb + v * EMB;
    float acc = bias[j];
    if (j < 32) acc += bias[GATES + j];      // recurrent bias, z and r gates only
#pragma unroll
    for (int e = 0; e < EMB; ++e)
        acc = fmaf(erow[e], kern[e * GATES + j], acc);
    proj[gid] = acc * LOG2E;
}

// ---------------- Phase 2: sequential GRU scan ----------------
__device__ __forceinline__ float sig2(float y) {
    return __builtin_amdgcn_rcpf(1.0f + __builtin_amdgcn_exp2f(-y));
}
__device__ __forceinline__ float rdlane(float v, int l) {
    return __int_as_float(__builtin_amdgcn_readlane(__float_as_int(v), l));
}

// Weights as NAMED SCALARS (R2/R4/R5 showed VGPR_Count<=68 with float arrays:
// arrays were lowered to scratch and reloaded every step, ~90 extra VALU
// instr/step). Rzr = {Rz,Rr} interleaved for v_pk_fma_f32.
#define DECL_W(k) \
    const v2f  Rzr##k = mk2(reck[k * GATES + u] * LOG2E,              \
                            reck[k * GATES + 16 + u] * LOG2E);        \
    const float Rh##k = reck[k * GATES + 32 + u] * LOG2E;

#define MAC(k) {                                   \
    const float hk = rdlane(h, k);                 \
    azr = fma2(Rzr##k, hk, azr);                   \
    ah  = fmaf(Rh##k, hk, ah); }

// One step: consume ring slot N (step T), refill it for step T+4 (id for T+4
// was loaded 4 steps ago; load id for T+8 now). id is wave-uniform -> scalar.
#define STEP(N, T) {                                             \
    v2f azr = xzr##N;          /* = x_z,x_r + all biases */      \
    const float xh = xh##N;                                      \
    float ah = bh;                                               \
    const float* p = proj + (size_t)id##N * GATES;               \
    xzr##N = mk2(p[u], p[16 + u]);   /* prefetch T+4 */          \
    xh##N  = p[32 + u];                                          \
    int tf = (T) + 8; if (tf >= SEQ) tf = SEQ - 1;               \
    id##N = idrow[tf];                                           \
    MAC(0)  MAC(1)  MAC(2)  MAC(3)                               \
    MAC(4)  MAC(5)  MAC(6)  MAC(7)                               \
    MAC(8)  MAC(9)  MAC(10) MAC(11)                              \
    MAC(12) MAC(13) MAC(14) MAC(15)                              \
    const float z  = sig2(azr.x);                                \
    const float r  = sig2(azr.y);                                \
    const float hh = sig2(fmaf(r, ah, xh));                      \
    h = fmaf(z, h - hh, hh); }

#define PRO(N) {                                                 \
    const float* p = proj + (size_t)idrow[N] * GATES;            \
    xzr##N = mk2(p[u], p[16 + u]);                               \
    xh##N  = p[32 + u];                                          \
    id##N  = idrow[4 + N]; }

__global__ __launch_bounds__(64, 1) void gru_scan(const int* __restrict__ ids,
                                                  const float* __restrict__ reck,
                                                  const float* __restrict__ bias,
                                                  const float* __restrict__ proj,
                                                  float* __restrict__ out) {
    const int lane = threadIdx.x & 63;
    const int u    = lane & 15;          // unit; lanes 16..63 mirror lanes 0..15
    const int b    = blockIdx.x;         // one batch row per wave, 256 waves
    const int* __restrict__ idrow = ids + (size_t)b * SEQ;

    DECL_W(0)  DECL_W(1)  DECL_W(2)  DECL_W(3)
    DECL_W(4)  DECL_W(5)  DECL_W(6)  DECL_W(7)
    DECL_W(8)  DECL_W(9)  DECL_W(10) DECL_W(11)
    DECL_W(12) DECL_W(13) DECL_W(14) DECL_W(15)
    const float bh = bias[GATES + 32 + u] * LOG2E;   // recurrent h-gate bias

    // 4-deep software-pipeline ring, all named scalars
    v2f  xzr0, xzr1, xzr2, xzr3;
    float xh0, xh1, xh2, xh3;
    int  id0, id1, id2, id3;
    PRO(0) PRO(1) PRO(2) PRO(3)

    float h = 0.0f;
    for (int t0 = 0; t0 < SEQ; t0 += 4) {
        STEP(0, t0)
        STEP(1, t0 + 1)
        STEP(2, t0 + 2)
        STEP(3, t0 + 3)
    }

    if (lane < UNITS) out[b * UNITS + u] = h;
}

extern "C" void kernel_launch(void* const* d_in, const int* in_sizes, int n_in,
                              void* d_out, int out_size, void* d_ws, size_t ws_size,
                              hipStream_t stream) {
    const int*   ids  = (const int*)d_in[0];
    const float* emb  = (const float*)d_in[1];
    const float* kern = (const float*)d_in[2];
    const float* reck = (const float*)d_in[3];
    const float* bias = (const float*)d_in[4];
    float* out  = (float*)d_out;
    float* proj = (float*)d_ws;   // 50001*48 floats = 9.6 MB scratch

    const int total = VOCAB_ROWS * GATES;
    proj_kernel<<<(total + 255) / 256, 256, 0, stream>>>(emb, kern, bias, proj);
    gru_scan<<<BATCH, 64, 0, stream>>>(ids, reck, bias, proj, out);
}